// Round 2
// baseline (667.447 us; speedup 1.0000x reference)
//
#include <hip/hip_runtime.h>

#define N_NODES 100000
#define N_EDGES 3200000
#define D 256

#define SCAT_BLOCKS 3125   // 800000 threads * 4 edges
#define GEMM_BLOCKS 1563   // 6250 waves (16 rows each) / 4 per block
#define CVT_BLOCKS  64     // 65536 W elems / (256*4)

using bf16x8 = __attribute__((ext_vector_type(8))) short;
using f32x4  = __attribute__((ext_vector_type(4))) float;
using i32x4  = __attribute__((ext_vector_type(4))) int;
using i32x2  = __attribute__((ext_vector_type(2))) int;

__device__ inline float bf2f(unsigned short b) {
    union { unsigned u; float f; } v; v.u = ((unsigned)b) << 16; return v.f;
}
__device__ inline unsigned short f2bf(float f) {
    union { float f; unsigned u; } v; v.f = f;
    unsigned u = v.u;
    u += 0x7FFFu + ((u >> 16) & 1u);   // round-to-nearest-even
    return (unsigned short)(u >> 16);
}

// ---- prep: blocks [0,64) convert W fp32->bf16; rest zero cnt ----
__global__ __launch_bounds__(256) void prep(const float* __restrict__ W,
                                            unsigned short* __restrict__ wb,
                                            int* __restrict__ cnt, int n_int4) {
    int bid = blockIdx.x;
    if (bid < CVT_BLOCKS) {
        int i = (bid * 256 + threadIdx.x) * 4;
        float4 f = *(const float4*)(W + i);
        ushort4 o;
        o.x = f2bf(f.x); o.y = f2bf(f.y); o.z = f2bf(f.z); o.w = f2bf(f.w);
        *(ushort4*)(wb + i) = o;
    } else {
        int t = (bid - CVT_BLOCKS) * 256 + threadIdx.x;
        if (t < n_int4) ((int4*)cnt)[t] = make_int4(0, 0, 0, 0);
    }
}

// ---- fused: GEMM (MFMA) || bucket scatter with XCD-chunked counters ----
// chunk = blockIdx % NCHUNK aligns with the HW's round-robin block->XCD mapping,
// so cnt[chunk][*] and csr sub-bucket lines stay XCD-local (no cross-XCD atomic
// line ping-pong). chunk is a pure function of blockIdx => bucket contents are
// deterministic; only speed depends on the actual XCD mapping.
template<int NCHUNK, int SUBCAP>
__global__ __launch_bounds__(256) void gemm_scatter(
    const float* __restrict__ x,            // [N_NODES, 256] fp32
    const unsigned short* __restrict__ wb,  // [256, 256] bf16
    unsigned short* __restrict__ sb,        // [N_NODES, 256] bf16 out
    const i32x4* __restrict__ erow4,
    const i32x4* __restrict__ ecol4,
    const f32x4* __restrict__ eval4,
    int* __restrict__ cnt,                  // [NCHUNK][N_NODES]
    i32x2* __restrict__ csr)                // [N_NODES][NCHUNK][SUBCAP]
{
    int bid = blockIdx.x;
    int r3 = bid % 3, g3 = bid / 3;
    if (r3 != 0) {
        // ---------- scatter role: h in [0,3125) ----------
        int h = 2 * g3 + (r3 - 1);
        int chunk = bid % NCHUNK;
        int t = h * 256 + threadIdx.x;              // exactly 800000 threads
        i32x4 r4 = __builtin_nontemporal_load(erow4 + t);
        i32x4 c4 = __builtin_nontemporal_load(ecol4 + t);
        f32x4 v4 = __builtin_nontemporal_load(eval4 + t);
        int rr[4], cc[4]; float vv[4];
#pragma unroll
        for (int j = 0; j < 4; ++j) { rr[j] = r4[j]; cc[j] = c4[j]; vv[j] = v4[j]; }
        int slot[4];
#pragma unroll
        for (int j = 0; j < 4; ++j)
            slot[j] = atomicAdd(&cnt[chunk * N_NODES + rr[j]], 1);
#pragma unroll
        for (int j = 0; j < 4; ++j) {
            if (slot[j] < SUBCAP) {
                i32x2 p; p[0] = cc[j]; p[1] = __float_as_int(vv[j]);
                csr[((size_t)rr[j] * NCHUNK + chunk) * SUBCAP + slot[j]] = p;
            }
        }
        return;
    }
    // ---------- GEMM role: g3 in [0,1563) ----------
    int wave = g3 * 4 + (int)(threadIdx.x >> 6);
    int m0 = wave << 4;
    if (m0 >= N_NODES) return;
    int lane = threadIdx.x & 63;
    int quad = lane >> 4;
    int r16  = lane & 15;

    const f32x4* arow = (const f32x4*)(x + (size_t)(m0 + r16) * D + quad * 8);
    const unsigned short* bbase = wb + (size_t)r16 * D + quad * 8;

    f32x4 acc[16];
#pragma unroll
    for (int t = 0; t < 16; ++t) acc[t] = (f32x4){0.f, 0.f, 0.f, 0.f};

    for (int k0 = 0; k0 < D; k0 += 32) {
        // x is read exactly once -> non-temporal (keep L3 for support/csr)
        f32x4 fa0 = __builtin_nontemporal_load(arow + (k0 >> 2));
        f32x4 fa1 = __builtin_nontemporal_load(arow + (k0 >> 2) + 1);
        bf16x8 a;
        a[0] = (short)f2bf(fa0[0]); a[1] = (short)f2bf(fa0[1]);
        a[2] = (short)f2bf(fa0[2]); a[3] = (short)f2bf(fa0[3]);
        a[4] = (short)f2bf(fa1[0]); a[5] = (short)f2bf(fa1[1]);
        a[6] = (short)f2bf(fa1[2]); a[7] = (short)f2bf(fa1[3]);
#pragma unroll
        for (int t = 0; t < 16; ++t) {
            bf16x8 b = *(const bf16x8*)(bbase + (size_t)t * 16 * D + k0);
            // swapped operands: lane holds 4 consecutive channels of one node
            acc[t] = __builtin_amdgcn_mfma_f32_16x16x32_bf16(b, a, acc[t], 0, 0, 0);
        }
    }

#pragma unroll
    for (int t = 0; t < 16; ++t) {
        ushort4 o;
        o.x = f2bf(acc[t][0]); o.y = f2bf(acc[t][1]);
        o.z = f2bf(acc[t][2]); o.w = f2bf(acc[t][3]);
        *(ushort4*)(sb + (size_t)(m0 + r16) * D + t * 16 + quad * 4) = o;
    }
}

// ---- pair-gather SpMM over NCHUNK sub-buckets, cross-chunk leftover stash ----
template<int NCHUNK, int SUBCAP>
__global__ __launch_bounds__(256) void spmm_gather(
    const int* __restrict__ cnt, const i32x2* __restrict__ csr,
    const unsigned short* __restrict__ sb, float* __restrict__ out)
{
    int wave = (int)((blockIdx.x * 256u + threadIdx.x) >> 6);
    if (wave >= N_NODES) return;
    int lane = threadIdx.x & 63;
    int hi = lane >> 5;                                  // 0: edge A, 1: edge B
    const unsigned short* base = sb + (size_t)(lane & 31) * 8;   // 8 ch/lane

    f32x4 A0 = {0.f,0.f,0.f,0.f}, B0 = {0.f,0.f,0.f,0.f};
    f32x4 A1 = {0.f,0.f,0.f,0.f}, B1 = {0.f,0.f,0.f,0.f};

#define PAIR2(PA, PB, AA, BB) do {                                   \
        int   col = hi ? (PB)[0] : (PA)[0];                          \
        float v   = __int_as_float(hi ? (PB)[1] : (PA)[1]);          \
        bf16x8 s = *(const bf16x8*)(base + ((size_t)col << 8));      \
        AA[0] += v * bf2f((unsigned short)s[0]);                     \
        AA[1] += v * bf2f((unsigned short)s[1]);                     \
        AA[2] += v * bf2f((unsigned short)s[2]);                     \
        AA[3] += v * bf2f((unsigned short)s[3]);                     \
        BB[0] += v * bf2f((unsigned short)s[4]);                     \
        BB[1] += v * bf2f((unsigned short)s[5]);                     \
        BB[2] += v * bf2f((unsigned short)s[6]);                     \
        BB[3] += v * bf2f((unsigned short)s[7]);                     \
    } while (0)

    i32x2 stash; int have = 0;       // wave-uniform control
#pragma unroll
    for (int c = 0; c < NCHUNK; ++c) {
        int dc = cnt[c * N_NODES + wave]; if (dc > SUBCAP) dc = SUBCAP;
        const i32x2* b0 = csr + ((size_t)wave * NCHUNK + c) * SUBCAP;
        int e = 0;
        for (; e + 4 <= dc; e += 4) {
            i32x2 p0 = b0[e], p1 = b0[e+1], p2 = b0[e+2], p3 = b0[e+3];
            PAIR2(p0, p1, A0, B0);
            PAIR2(p2, p3, A1, B1);
        }
        if (e + 2 <= dc) {
            i32x2 p0 = b0[e], p1 = b0[e+1];
            PAIR2(p0, p1, A0, B0);
            e += 2;
        }
        if (e < dc) {
            i32x2 last = b0[e];
            if (have) { PAIR2(stash, last, A1, B1); have = 0; }
            else      { stash = last; have = 1; }
        }
    }
    if (have) {                       // final odd edge: hi half contributes 0
        int   col = stash[0];
        float v   = hi ? 0.f : __int_as_float(stash[1]);
        bf16x8 s = *(const bf16x8*)(base + ((size_t)col << 8));
        A0[0] += v * bf2f((unsigned short)s[0]);
        A0[1] += v * bf2f((unsigned short)s[1]);
        A0[2] += v * bf2f((unsigned short)s[2]);
        A0[3] += v * bf2f((unsigned short)s[3]);
        B0[0] += v * bf2f((unsigned short)s[4]);
        B0[1] += v * bf2f((unsigned short)s[5]);
        B0[2] += v * bf2f((unsigned short)s[6]);
        B0[3] += v * bf2f((unsigned short)s[7]);
    }
#undef PAIR2

    f32x4 A = A0 + A1;
    f32x4 B = B0 + B1;
#pragma unroll
    for (int j = 0; j < 4; ++j) {
        A[j] += __shfl_xor(A[j], 32);
        B[j] += __shfl_xor(B[j], 32);
    }
    if (lane < 32) {
        float* o = out + (size_t)wave * D + lane * 8;
        __builtin_nontemporal_store(A, (f32x4*)o);
        __builtin_nontemporal_store(B, (f32x4*)(o + 4));
    }
}

// ---- geometry-templated launcher ----
template<int NCHUNK, int SUBCAP>
static void launch_all(const float* x, const float* W, const int* erow,
                       const int* ecol, const float* eval, float* out,
                       char* ws, hipStream_t stream) {
    unsigned short* wb  = (unsigned short*)(ws + 0);         // 131,072
    unsigned short* sb  = (unsigned short*)(ws + 131072);    // 51,200,000
    int*            cnt = (int*)(ws + 51331072);             // up to 3,200,000
    i32x2*          csr = (i32x2*)(ws + 54531072);           // NCHUNK*SUBCAP*8*N

    int n_int4 = NCHUNK * N_NODES / 4;
    int zero_blocks = (n_int4 + 255) / 256;
    prep<<<CVT_BLOCKS + zero_blocks, 256, 0, stream>>>(W, wb, cnt, n_int4);

    gemm_scatter<NCHUNK, SUBCAP><<<SCAT_BLOCKS + GEMM_BLOCKS, 256, 0, stream>>>(
        x, wb, sb, (const i32x4*)erow, (const i32x4*)ecol, (const f32x4*)eval,
        cnt, csr);

    spmm_gather<NCHUNK, SUBCAP><<<N_NODES / 4, 256, 0, stream>>>(cnt, csr, sb, out);
}

extern "C" void kernel_launch(void* const* d_in, const int* in_sizes, int n_in,
                              void* d_out, int out_size, void* d_ws, size_t ws_size,
                              hipStream_t stream) {
    const float* x    = (const float*)d_in[0];
    const float* W    = (const float*)d_in[1];
    const int*   erow = (const int*)d_in[2];
    const int*   ecol = (const int*)d_in[3];
    const float* eval = (const float*)d_in[4];
    float* out = (float*)d_out;
    char*  ws  = (char*)d_ws;

    const size_t base = 54531072;                         // wb + sb + cnt
    auto need = [&](int nch, int sc) {
        return base + (size_t)N_NODES * nch * sc * 8;
    };
    // Preferred: 8 chunks (XCD-aligned), SUBCAP=20 (lambda=4/bucket) -> 182.5 MB
    // Fallbacks shrink chunk count; (1,80) is the round-1 layout (115.7 MB, known-good).
    if (ws_size >= need(8, 20))      launch_all<8, 20>(x, W, erow, ecol, eval, out, ws, stream);
    else if (ws_size >= need(4, 28)) launch_all<4, 28>(x, W, erow, ecol, eval, out, ws, stream);
    else if (ws_size >= need(2, 44)) launch_all<2, 44>(x, W, erow, ecol, eval, out, ws, stream);
    else                             launch_all<1, 80>(x, W, erow, ecol, eval, out, ws, stream);
}

// Round 3
// 583.620 us; speedup vs baseline: 1.1436x; 1.1436x over previous
//
#include <hip/hip_runtime.h>

#define N_NODES 100000
#define N_EDGES 3200000
#define D 256

#define NBKT 391           // row-buckets of 256 rows each (391*256 = 100096)
#define BCAP 9216          // entries per bucket region; mean 8184, ~11 sigma margin
#define P1_BLOCKS 782      // ceil(3.2M / 4096 edges per block)
#define GEMM_BLOCKS 1563   // 6250 waves (16 rows each) / 4 per block
#define CVT_BLOCKS 64      // 65536 W elems / (256*4)

using bf16x8 = __attribute__((ext_vector_type(8))) short;
using f32x4  = __attribute__((ext_vector_type(4))) float;
using i32x4  = __attribute__((ext_vector_type(4))) int;
using i32x2  = __attribute__((ext_vector_type(2))) int;

__device__ inline float bf2f(unsigned short b) {
    union { unsigned u; float f; } v; v.u = ((unsigned)b) << 16; return v.f;
}
__device__ inline unsigned short f2bf(float f) {
    union { float f; unsigned u; } v; v.f = f;
    unsigned u = v.u;
    u += 0x7FFFu + ((u >> 16) & 1u);   // round-to-nearest-even
    return (unsigned short)(u >> 16);
}

// ---- prep: [0,64) convert W fp32->bf16; [64,66) init bucket_next ----
__global__ __launch_bounds__(256) void prep(const float* __restrict__ W,
                                            unsigned short* __restrict__ wb,
                                            int* __restrict__ bucket_next) {
    int bid = blockIdx.x;
    if (bid < CVT_BLOCKS) {
        int i = (bid * 256 + threadIdx.x) * 4;
        float4 f = *(const float4*)(W + i);
        ushort4 o;
        o.x = f2bf(f.x); o.y = f2bf(f.y); o.z = f2bf(f.z); o.w = f2bf(f.w);
        *(ushort4*)(wb + i) = o;
    } else {
        int t = (bid - CVT_BLOCKS) * 256 + threadIdx.x;
        if (t < NBKT) bucket_next[t] = t * BCAP;
    }
}

// ---- fused: GEMM (MFMA) || edge partition into row-buckets ----
// Partition role: per-edge ranking via LDS atomics (CU-local, cheap);
// only 391 global atomics per block (space reservation) -> ~306K total,
// 42x fewer memory-side RMWs than the per-edge scheme (the measured
// ~20 atomics/cycle device-wide wall).
__global__ __launch_bounds__(256) void gemm_part(
    const float* __restrict__ x,            // [N_NODES, 256] fp32
    const unsigned short* __restrict__ wb,  // [256, 256] bf16
    unsigned short* __restrict__ sb,        // [N_NODES, 256] bf16 out
    const i32x4* __restrict__ erow4,
    const i32x4* __restrict__ ecol4,
    const f32x4* __restrict__ eval4,
    int* __restrict__ bucket_next,          // [NBKT], pre-set to b*BCAP
    i32x2* __restrict__ bkt)                // [NBKT*BCAP] partitioned edges
{
    __shared__ int h_cnt[NBKT];
    __shared__ int h_base[NBKT];
    int bid = blockIdx.x;
    int r3 = bid % 3, g3 = bid / 3;
    if (r3 == 0) {
        // ---------- partition role: p in [0, 782) ----------
        int p = g3;
        int tid = threadIdx.x;
        for (int i = tid; i < NBKT; i += 256) h_cnt[i] = 0;
        __syncthreads();
        int e0 = p * 4096;
        int jmax = (N_EDGES - e0) >> 10; if (jmax > 4) jmax = 4;  // 1024-edge quarters
        int w0[4][4], w1[4][4], bs[4][4];
#pragma unroll
        for (int j = 0; j < 4; ++j) {
            if (j < jmax) {
                int q = p * 1024 + j * 256 + tid;          // i32x4 index
                i32x4 r4 = __builtin_nontemporal_load(erow4 + q);
                i32x4 c4 = __builtin_nontemporal_load(ecol4 + q);
                f32x4 v4 = __builtin_nontemporal_load(eval4 + q);
#pragma unroll
                for (int k = 0; k < 4; ++k) {
                    int row = r4[k];
                    int b   = row >> 8;
                    int rl  = row & 255;
                    int slot = atomicAdd(&h_cnt[b], 1);    // LDS atomic, returning
                    w0[j][k] = c4[k] | (rl << 24);
                    w1[j][k] = __float_as_int(v4[k]);
                    bs[j][k] = (b << 14) | slot;           // slot < 4096 fits 14b
                }
            }
        }
        __syncthreads();
        for (int i = tid; i < NBKT; i += 256)
            h_base[i] = atomicAdd(&bucket_next[i], h_cnt[i]);  // global, ~391/block
        __syncthreads();
#pragma unroll
        for (int j = 0; j < 4; ++j) {
            if (j < jmax) {
#pragma unroll
                for (int k = 0; k < 4; ++k) {
                    int b    = bs[j][k] >> 14;
                    int slot = bs[j][k] & 16383;
                    int dst  = h_base[b] + slot;
                    if (dst < (b + 1) * BCAP) {            // ~11-sigma safety clamp
                        i32x2 o; o[0] = w0[j][k]; o[1] = w1[j][k];
                        bkt[dst] = o;
                    }
                }
            }
        }
        return;
    }
    // ---------- GEMM role: g = 2*g3 + (r3-1) in [0, 1564) ----------
    int g = 2 * g3 + (r3 - 1);
    int wave = g * 4 + (int)(threadIdx.x >> 6);
    int m0 = wave << 4;
    if (m0 >= N_NODES) return;
    int lane = threadIdx.x & 63;
    int quad = lane >> 4;
    int r16  = lane & 15;

    const f32x4* arow = (const f32x4*)(x + (size_t)(m0 + r16) * D + quad * 8);
    const unsigned short* bbase = wb + (size_t)r16 * D + quad * 8;

    f32x4 acc[16];
#pragma unroll
    for (int t = 0; t < 16; ++t) acc[t] = (f32x4){0.f, 0.f, 0.f, 0.f};

    for (int k0 = 0; k0 < D; k0 += 32) {
        f32x4 fa0 = __builtin_nontemporal_load(arow + (k0 >> 2));
        f32x4 fa1 = __builtin_nontemporal_load(arow + (k0 >> 2) + 1);
        bf16x8 a;
        a[0] = (short)f2bf(fa0[0]); a[1] = (short)f2bf(fa0[1]);
        a[2] = (short)f2bf(fa0[2]); a[3] = (short)f2bf(fa0[3]);
        a[4] = (short)f2bf(fa1[0]); a[5] = (short)f2bf(fa1[1]);
        a[6] = (short)f2bf(fa1[2]); a[7] = (short)f2bf(fa1[3]);
#pragma unroll
        for (int t = 0; t < 16; ++t) {
            bf16x8 b = *(const bf16x8*)(bbase + (size_t)t * 16 * D + k0);
            // swapped operands: lane holds 4 consecutive channels of one node
            acc[t] = __builtin_amdgcn_mfma_f32_16x16x32_bf16(b, a, acc[t], 0, 0, 0);
        }
    }

#pragma unroll
    for (int t = 0; t < 16; ++t) {
        ushort4 o;
        o.x = f2bf(acc[t][0]); o.y = f2bf(acc[t][1]);
        o.z = f2bf(acc[t][2]); o.w = f2bf(acc[t][3]);
        *(ushort4*)(sb + (size_t)(m0 + r16) * D + t * 16 + quad * 4) = o;
    }
}

// ---- pass2: group each bucket by row, in place (csr aliases bkt) ----
// One 1024-thread block per bucket. All reads staged to registers before
// any write; blocks touch only their own region -> aliasing is safe.
__global__ __launch_bounds__(1024) void build_csr(
    const int* __restrict__ bucket_next,
    i32x2* __restrict__ bkt,               // in: partitioned, out: row-grouped
    int* __restrict__ rowptr, int* __restrict__ cntout)
{
    __shared__ int cnt[256];
    __shared__ int scn[256];
    int b = blockIdx.x;
    int tid = threadIdx.x;
    int base = b * BCAP;
    int ne = bucket_next[b] - base; if (ne > BCAP) ne = BCAP;

    if (tid < 256) cnt[tid] = 0;
    __syncthreads();

    int w0[9], w1[9], sp[9];
#pragma unroll
    for (int j = 0; j < 9; ++j) {          // 9*1024 = 9216 = BCAP coverage
        int idx = j * 1024 + tid;
        sp[j] = -1;
        if (idx < ne) {
            i32x2 e = bkt[base + idx];
            w0[j] = e[0]; w1[j] = e[1];
            int rl = ((unsigned)e[0]) >> 24;
            int s  = atomicAdd(&cnt[rl], 1);   // LDS atomic, returning
            sp[j] = (rl << 16) | s;            // s < 9216 fits 16b
        }
    }
    __syncthreads();
    if (tid < 256) scn[tid] = cnt[tid];
    __syncthreads();
    for (int off = 1; off < 256; off <<= 1) {  // Hillis-Steele inclusive scan
        int v = 0;
        if (tid < 256 && tid >= off) v = scn[tid - off];
        __syncthreads();
        if (tid < 256) scn[tid] += v;
        __syncthreads();
    }
    if (tid < 256) {
        int excl = scn[tid] - cnt[tid];
        scn[tid] = excl;                        // reuse as exclusive offsets
        int row = (b << 8) + tid;
        if (row < N_NODES) {
            rowptr[row] = base + excl;
            cntout[row] = cnt[tid];
        }
    }
    __syncthreads();
#pragma unroll
    for (int j = 0; j < 9; ++j) {
        if (sp[j] >= 0) {
            int rl = sp[j] >> 16, s = sp[j] & 0xFFFF;
            i32x2 o; o[0] = w0[j] & 0x00FFFFFF; o[1] = w1[j];
            bkt[base + scn[rl] + s] = o;
        }
    }
}

// ---- pair-gather SpMM: 2 edges per instruction (half-wave split) ----
__global__ __launch_bounds__(256) void spmm_gather(
    const int* __restrict__ rowptr, const int* __restrict__ cntout,
    const i32x2* __restrict__ csr,
    const unsigned short* __restrict__ sb, float* __restrict__ out)
{
    int wave = (int)((blockIdx.x * 256u + threadIdx.x) >> 6);
    if (wave >= N_NODES) return;
    int lane = threadIdx.x & 63;
    int hi = lane >> 5;                                  // 0: edge A, 1: edge B
    const unsigned short* base = sb + (size_t)(lane & 31) * 8;   // 8 ch/lane

    int beg = rowptr[wave];
    int end = beg + cntout[wave];

    f32x4 a0 = {0.f,0.f,0.f,0.f}, b0 = {0.f,0.f,0.f,0.f};
    f32x4 a1 = {0.f,0.f,0.f,0.f}, b1 = {0.f,0.f,0.f,0.f};
    f32x4 a2 = {0.f,0.f,0.f,0.f}, b2 = {0.f,0.f,0.f,0.f};
    f32x4 a3 = {0.f,0.f,0.f,0.f}, b3 = {0.f,0.f,0.f,0.f};

#define PAIR(AA, BB, EE) do {                                        \
        i32x2 pa = __builtin_nontemporal_load(csr + (EE));           \
        i32x2 pb = __builtin_nontemporal_load(csr + (EE) + 1);       \
        int   col = hi ? pb[0] : pa[0];                              \
        float v   = __int_as_float(hi ? pb[1] : pa[1]);              \
        bf16x8 s = *(const bf16x8*)(base + ((size_t)col << 8));      \
        AA[0] += v * bf2f((unsigned short)s[0]);                     \
        AA[1] += v * bf2f((unsigned short)s[1]);                     \
        AA[2] += v * bf2f((unsigned short)s[2]);                     \
        AA[3] += v * bf2f((unsigned short)s[3]);                     \
        BB[0] += v * bf2f((unsigned short)s[4]);                     \
        BB[1] += v * bf2f((unsigned short)s[5]);                     \
        BB[2] += v * bf2f((unsigned short)s[6]);                     \
        BB[3] += v * bf2f((unsigned short)s[7]);                     \
    } while (0)

    int e = beg;
    for (; e + 8 <= end; e += 8) {
        PAIR(a0, b0, e);
        PAIR(a1, b1, e + 2);
        PAIR(a2, b2, e + 4);
        PAIR(a3, b3, e + 6);
    }
    for (; e + 2 <= end; e += 2) PAIR(a0, b0, e);
    if (e < end) {                                   // odd tail: hi half idle
        i32x2 pa = __builtin_nontemporal_load(csr + e);
        int   col = pa[0];
        float v   = hi ? 0.f : __int_as_float(pa[1]);
        bf16x8 s = *(const bf16x8*)(base + ((size_t)col << 8));
        a0[0] += v * bf2f((unsigned short)s[0]);
        a0[1] += v * bf2f((unsigned short)s[1]);
        a0[2] += v * bf2f((unsigned short)s[2]);
        a0[3] += v * bf2f((unsigned short)s[3]);
        b0[0] += v * bf2f((unsigned short)s[4]);
        b0[1] += v * bf2f((unsigned short)s[5]);
        b0[2] += v * bf2f((unsigned short)s[6]);
        b0[3] += v * bf2f((unsigned short)s[7]);
    }
#undef PAIR

    f32x4 A = (a0 + a1) + (a2 + a3);
    f32x4 B = (b0 + b1) + (b2 + b3);
#pragma unroll
    for (int j = 0; j < 4; ++j) {
        A[j] += __shfl_xor(A[j], 32);
        B[j] += __shfl_xor(B[j], 32);
    }
    if (lane < 32) {
        float* o = out + (size_t)wave * D + lane * 8;
        __builtin_nontemporal_store(A, (f32x4*)o);
        __builtin_nontemporal_store(B, (f32x4*)(o + 4));
    }
}

extern "C" void kernel_launch(void* const* d_in, const int* in_sizes, int n_in,
                              void* d_out, int out_size, void* d_ws, size_t ws_size,
                              hipStream_t stream) {
    const float* x    = (const float*)d_in[0];
    const float* W    = (const float*)d_in[1];
    const int*   erow = (const int*)d_in[2];
    const int*   ecol = (const int*)d_in[3];
    const float* eval = (const float*)d_in[4];
    float* out = (float*)d_out;

    // ---- workspace layout (bytes) ----
    char* ws = (char*)d_ws;
    unsigned short* wb     = (unsigned short*)(ws + 0);          // 131,072
    unsigned short* sb     = (unsigned short*)(ws + 131072);     // 51,200,000
    int*            bnext  = (int*)(ws + 51331072);              // 1,564 (4KB pad)
    int*            rowptr = (int*)(ws + 51335168);              // 400,000
    int*            cnt    = (int*)(ws + 51735168);              // 400,000
    i32x2*          bkt    = (i32x2*)(ws + 52135168);            // 28,827,648
    // total 80,962,816 bytes (~81 MB); csr aliases bkt (in-place regroup)

    prep<<<CVT_BLOCKS + 2, 256, 0, stream>>>(W, wb, bnext);

    gemm_part<<<3 * P1_BLOCKS, 256, 0, stream>>>(
        x, wb, sb, (const i32x4*)erow, (const i32x4*)ecol, (const f32x4*)eval,
        bnext, bkt);

    build_csr<<<NBKT, 1024, 0, stream>>>(bnext, bkt, rowptr, cnt);

    spmm_gather<<<N_NODES / 4, 256, 0, stream>>>(rowptr, cnt, bkt, sb, out);
}